// Round 8
// baseline (9000.365 us; speedup 1.0000x reference)
//
#include <hip/hip_runtime.h>
#include <hip/hip_bf16.h>
#include <math.h>

#define SEQ 2048
#define HIDDEN 2048
#define NHEAD 32
#define NKVH 8
#define HD 64
#define QKVW 3072

typedef __bf16 bf16_t;

// ---------- sentinel fill (contract-violation signal), f32 ----------
__global__ __launch_bounds__(256) void k_fill(float* __restrict__ out, int n, float v) {
  int i = blockIdx.x * 256 + threadIdx.x;
  if (i < n) out[i] = v;
}

// ---------- naive GEMM1: qkvF[bs][n] = sum_k hid[bs][k] * Wqkv[k][n] ----------
__global__ __launch_bounds__(256) void n_gemm1(const float* __restrict__ hid,
                                               const float* __restrict__ w,
                                               float* __restrict__ out) {
  const int bs = blockIdx.y;
  const int n = blockIdx.x * 256 + threadIdx.x;
  const float* hrow = hid + (size_t)bs * HIDDEN;
  float acc = 0.f;
  for (int k = 0; k < HIDDEN; ++k)
    acc = fmaf(hrow[k], w[(size_t)k * QKVW + n], acc);
  out[(size_t)bs * QKVW + n] = acc;
}

// ---------- naive RoPE + split; positions decoded adaptively (int32 OR f32) ----------
__global__ __launch_bounds__(256) void n_rope(const float* __restrict__ qkv,
                                              const unsigned* __restrict__ pos,
                                              float* __restrict__ qF,
                                              float* __restrict__ kF,
                                              float* __restrict__ vF) {
  const int bs = blockIdx.x;            // b*SEQ + s
  const unsigned u = pos[bs];
  const float p = (u >= 0x3F800000u) ? __uint_as_float(u) : (float)(int)u;
  const float* row = qkv + (size_t)bs * QKVW;
  for (int t = threadIdx.x; t < 1792; t += 256) {
    if (t < 1280) {                     // rotate q (t<1024) / k pairs
      const bool isq = t < 1024;
      const int tt = isq ? t : t - 1024;
      const int hh = tt >> 5, d = tt & 31;
      const int col = isq ? (hh * HD + d) : (NHEAD * HD + hh * HD + d);
      float x1 = row[col];
      float x2 = row[col + 32];
      float fr = p * exp2f((float)d * -0.41524101186092029f);  // 10000^(-d/32)
      float sn, cs;
      sincosf(fr, &sn, &cs);
      float o1 = x1 * cs - x2 * sn;
      float o2 = x2 * cs + x1 * sn;
      if (isq) {
        size_t base = ((size_t)bs * NHEAD + hh) * HD + d;   // (B,S,NH,HD)
        qF[base] = o1; qF[base + 32] = o2;
      } else {
        size_t base = ((size_t)bs * NKVH + hh) * HD + d;    // (B,S,NKV,HD)
        kF[base] = o1; kF[base + 32] = o2;
      }
    } else {                            // v passthrough
      const int tt = t - 1280;          // < 512
      const int hh = tt >> 6, d = tt & 63;
      vF[((size_t)bs * NKVH + hh) * HD + d] = row[(NHEAD + NKVH) * HD + hh * HD + d];
    }
  }
}

// ---------- naive VALU flash attention, f32, scale on scores ----------
__global__ __launch_bounds__(256) void n_attn(const float* __restrict__ qF,
                                              const float* __restrict__ kF,
                                              const float* __restrict__ vF,
                                              float* __restrict__ attnF) {
  __shared__ float Kf[32][64];
  __shared__ float Vf[32][64];
  const int chunk = blockIdx.x;
  const int bh = blockIdx.y;
  const int b = bh >> 5, h = bh & 31;
  const int kvh = h >> 2;               // GROUP=4
  const int tid = threadIdx.x;
  const int r = chunk * 256 + tid;

  float q[64];
  const float* qp = qF + (((size_t)b * SEQ + r) * NHEAD + h) * HD;
#pragma unroll
  for (int d = 0; d < 64; ++d) q[d] = qp[d];

  float acc[64];
#pragma unroll
  for (int d = 0; d < 64; ++d) acc[d] = 0.f;
  float m = -1e30f, l = 0.f;

  const int ntile = chunk * 8 + 8;
  for (int kc = 0; kc < ntile; ++kc) {
    const int k0 = kc * 32;
    __syncthreads();
    for (int i = tid; i < 2048; i += 256) {
      int kk = i >> 6, d = i & 63;
      Kf[kk][d] = kF[(((size_t)b * SEQ + k0 + kk) * NKVH + kvh) * HD + d];
      Vf[kk][d] = vF[(((size_t)b * SEQ + k0 + kk) * NKVH + kvh) * HD + d];
    }
    __syncthreads();
    if (k0 > r) continue;

    float s[32];
#pragma unroll
    for (int j = 0; j < 32; ++j) {
      float a = 0.f;
#pragma unroll
      for (int d = 0; d < 64; ++d) a = fmaf(q[d], Kf[j][d], a);
      s[j] = 0.125f * a;
      if (k0 + j > r) s[j] = -1e30f;
    }
    float tmax = s[0];
#pragma unroll
    for (int j = 1; j < 32; ++j) tmax = fmaxf(tmax, s[j]);
    float mn = fmaxf(m, tmax);
    float scale = __expf(m - mn);
    m = mn;
    l *= scale;
#pragma unroll
    for (int d = 0; d < 64; ++d) acc[d] *= scale;
#pragma unroll
    for (int j = 0; j < 32; ++j) {
      float pj = __expf(s[j] - mn);
      l += pj;
#pragma unroll
      for (int d = 0; d < 64; ++d) acc[d] = fmaf(pj, Vf[j][d], acc[d]);
    }
  }

  const float inv = 1.f / l;
  float* op = attnF + ((size_t)b * SEQ + r) * HIDDEN + h * HD;
#pragma unroll
  for (int d = 0; d < 64; ++d) op[d] = acc[d] * inv;
}

// ---------- naive GEMM2: out[bs][n] = sum_k attnF[bs][k] * Wo[k][n], F32 STORE ----------
__global__ __launch_bounds__(256) void n_gemm2(const float* __restrict__ attnF,
                                               const float* __restrict__ wo,
                                               float* __restrict__ out) {
  const int bs = blockIdx.y;
  const int n = blockIdx.x * 256 + threadIdx.x;
  const float* arow = attnF + (size_t)bs * HIDDEN;
  float acc = 0.f;
  for (int k = 0; k < HIDDEN; ++k)
    acc = fmaf(arow[k], wo[(size_t)k * HIDDEN + n], acc);
  out[(size_t)bs * HIDDEN + n] = acc;   // f32 output — reference returns float32
}

extern "C" void kernel_launch(void* const* d_in, const int* in_sizes, int n_in,
                              void* d_out, int out_size, void* d_ws, size_t ws_size,
                              hipStream_t stream) {
  float* out = (float*)d_out;

  // ---- contract checks (host-visible constants -> graph-safe branches) ----
  if (n_in != 4) { k_fill<<<dim3(32768), dim3(256), 0, stream>>>(out, 8388608, 222.0f); return; }
  if (out_size != 8388608) { k_fill<<<dim3(32768), dim3(256), 0, stream>>>(out, 8388608, 111.0f); return; }
  if (ws_size < (size_t)134217728) { k_fill<<<dim3(32768), dim3(256), 0, stream>>>(out, 8388608, 777.0f); return; }

  // ---- rank-match inputs by size (immune to input-order & size-unit changes) ----
  // Element counts: hidden 8388608 > Wqkv 6291456 > Wo 4194304 > positions 4096.
  int ord[4] = {0, 1, 2, 3};
  for (int i = 1; i < 4; ++i)
    for (int j = i; j > 0 && in_sizes[ord[j]] > in_sizes[ord[j - 1]]; --j) {
      int t = ord[j]; ord[j] = ord[j - 1]; ord[j - 1] = t;
    }
  if (in_sizes[ord[0]] == in_sizes[ord[1]] || in_sizes[ord[1]] == in_sizes[ord[2]] ||
      in_sizes[ord[2]] == in_sizes[ord[3]]) {
    k_fill<<<dim3(32768), dim3(256), 0, stream>>>(out, 8388608, 333.0f);
    return;
  }
  const float*    hidden    = (const float*)d_in[ord[0]];
  const float*    wqkv      = (const float*)d_in[ord[1]];
  const float*    wo        = (const float*)d_in[ord[2]];
  const unsigned* positions = (const unsigned*)d_in[ord[3]];

  // f32 scratch, no overlap: 128 MiB.
  char* ws = (char*)d_ws;
  float* qkvF  = (float*)(ws + 0);           // 48 MiB
  float* qF    = (float*)(ws + 50331648);    // 32 MiB
  float* kF    = (float*)(ws + 83886080);    //  8 MiB
  float* vF    = (float*)(ws + 92274688);    //  8 MiB
  float* attnF = (float*)(ws + 100663296);   // 32 MiB

  n_gemm1<<<dim3(12, 4096), dim3(256), 0, stream>>>(hidden, wqkv, qkvF);
  n_rope<<<dim3(4096), dim3(256), 0, stream>>>(qkvF, positions, qF, kF, vF);
  n_attn<<<dim3(8, 64), dim3(256), 0, stream>>>(qF, kF, vF, attnF);
  n_gemm2<<<dim3(8, 4096), dim3(256), 0, stream>>>(attnF, wo, out);
}

// Round 9
// 519.113 us; speedup vs baseline: 17.3380x; 17.3380x over previous
//
#include <hip/hip_runtime.h>
#include <hip/hip_bf16.h>
#include <math.h>

#define SEQ 2048
#define HIDDEN 2048
#define NHEAD 32
#define NKVH 8
#define HD 64
#define QKVW 3072  // (NH + 2*NKV) * HD

typedef __bf16 bf16_t;
typedef __bf16 bf16x8 __attribute__((ext_vector_type(8)));
typedef __bf16 bf16x4 __attribute__((ext_vector_type(4)));
typedef float f32x4 __attribute__((ext_vector_type(4)));

// ---------- sentinel fill (contract-violation signal), f32 ----------
__global__ __launch_bounds__(256) void k_fill(float* __restrict__ out, int n, float v) {
  int i = blockIdx.x * 256 + threadIdx.x;
  if (i < n) out[i] = v;
}

// ---------------- f32 -> bf16 convert, 4 elems/thread ----------------
__global__ __launch_bounds__(256) void k_cvt(const float* __restrict__ in,
                                             bf16_t* __restrict__ out, int n4) {
  int i = blockIdx.x * 256 + threadIdx.x;
  if (i >= n4) return;
  float4 v = ((const float4*)in)[i];
  bf16x4 o;
  o[0] = (bf16_t)v.x; o[1] = (bf16_t)v.y; o[2] = (bf16_t)v.z; o[3] = (bf16_t)v.w;
  ((bf16x4*)out)[i] = o;
}

// ------- transpose + convert: in (R x C) f32 row-major -> out (C x R) bf16 -------
__global__ __launch_bounds__(256) void k_tconv(const float* __restrict__ in,
                                               bf16_t* __restrict__ out, int R, int C) {
  __shared__ float t[64][65];  // +1 pad breaks bank conflicts on transposed read
  const int c0 = blockIdx.x * 64, r0 = blockIdx.y * 64;
#pragma unroll
  for (int i = 0; i < 16; ++i) {
    int idx = threadIdx.x + i * 256;
    int r = idx >> 6, c = idx & 63;
    t[r][c] = in[(size_t)(r0 + r) * C + c0 + c];
  }
  __syncthreads();
#pragma unroll
  for (int i = 0; i < 16; ++i) {
    int idx = threadIdx.x + i * 256;
    int nr = idx >> 6, kc = idx & 63;
    out[(size_t)(c0 + nr) * R + r0 + kc] = (bf16_t)t[kc][nr];
  }
}

// ---------------- bf16 GEMM: C[M,N] = A[M,K] * Bt[N,K]^T ----------------
// m97 structure: 128x128 tile, BK=32, 16x16x32 MFMA, 4 waves x (4x4) frags.
// OutT = bf16 (intermediates) or float (final output).
template <typename OutT>
__global__ __launch_bounds__(256) void k_gemm(const bf16_t* __restrict__ A,
                                              const bf16_t* __restrict__ Bt,
                                              OutT* __restrict__ C,
                                              int M, int N, int K) {
  __shared__ __align__(16) bf16_t As[128 * 32];
  __shared__ __align__(16) bf16_t Bs[128 * 32];
  const int tid  = threadIdx.x;
  const int wave = tid >> 6, lane = tid & 63;
  const int lr = lane & 15, quad = lane >> 4;
  const int mtile = blockIdx.y * 128, ntile = blockIdx.x * 128;
  const int wm = (wave & 1) * 64, wn = (wave >> 1) * 64;
  const int c0 = wave * 128 + lane, c1 = c0 + 64;  // 16B chunk ids, 512 total

  const bf16_t* aG0 = A  + (size_t)(mtile + (c0 >> 2)) * K + (c0 & 3) * 8;
  const bf16_t* aG1 = A  + (size_t)(mtile + (c1 >> 2)) * K + (c1 & 3) * 8;
  const bf16_t* bG0 = Bt + (size_t)(ntile + (c0 >> 2)) * K + (c0 & 3) * 8;
  const bf16_t* bG1 = Bt + (size_t)(ntile + (c1 >> 2)) * K + (c1 & 3) * 8;
  bf16_t* lA0 = As + c0 * 8; bf16_t* lA1 = As + c1 * 8;
  bf16_t* lB0 = Bs + c0 * 8; bf16_t* lB1 = Bs + c1 * 8;

  f32x4 acc[4][4];
  const f32x4 z4 = {0.f, 0.f, 0.f, 0.f};
#pragma unroll
  for (int mf = 0; mf < 4; ++mf)
#pragma unroll
    for (int nf = 0; nf < 4; ++nf) acc[mf][nf] = z4;

  for (int kt = 0; kt < K; kt += 32) {
    bf16x8 va0 = *(const bf16x8*)(aG0 + kt);
    bf16x8 va1 = *(const bf16x8*)(aG1 + kt);
    bf16x8 vb0 = *(const bf16x8*)(bG0 + kt);
    bf16x8 vb1 = *(const bf16x8*)(bG1 + kt);
    __syncthreads();   // prior iter's LDS reads done before overwrite
    *(bf16x8*)lA0 = va0; *(bf16x8*)lA1 = va1;
    *(bf16x8*)lB0 = vb0; *(bf16x8*)lB1 = vb1;
    __syncthreads();   // tiles resident
    bf16x8 af[4], bfr[4];
#pragma unroll
    for (int mf = 0; mf < 4; ++mf)
      af[mf] = *(const bf16x8*)(As + (wm + mf * 16 + lr) * 32 + quad * 8);
#pragma unroll
    for (int nf = 0; nf < 4; ++nf)
      bfr[nf] = *(const bf16x8*)(Bs + (wn + nf * 16 + lr) * 32 + quad * 8);
#pragma unroll
    for (int mf = 0; mf < 4; ++mf)
#pragma unroll
      for (int nf = 0; nf < 4; ++nf)
        acc[mf][nf] = __builtin_amdgcn_mfma_f32_16x16x32_bf16(af[mf], bfr[nf], acc[mf][nf], 0, 0, 0);
  }
  // C/D layout: col=lane&15, row=quad*4+reg  [m89/m91]
#pragma unroll
  for (int mf = 0; mf < 4; ++mf)
#pragma unroll
    for (int nf = 0; nf < 4; ++nf)
#pragma unroll
      for (int r = 0; r < 4; ++r)
        C[(size_t)(mtile + wm + mf * 16 + quad * 4 + r) * N + ntile + wn + nf * 16 + lr] =
            (OutT)acc[mf][nf][r];
}

// -------- RoPE: qkv bf16 -> ql (b,h,s,hd)*0.125, kl (b,kvh,s,hd); pos adaptive --------
__global__ __launch_bounds__(256) void k_rope(const bf16_t* __restrict__ qkv,
                                              const unsigned* __restrict__ pos,
                                              bf16_t* __restrict__ ql,
                                              bf16_t* __restrict__ kl) {
  const int bs = blockIdx.x;            // b*SEQ + s
  const int b = bs >> 11, s = bs & 2047;
  const unsigned u = pos[bs];
  const float p = (u >= 0x3F800000u) ? __uint_as_float(u) : (float)(int)u;
  for (int t = threadIdx.x; t < 1280; t += 256) {
    const bool isq = t < 1024;
    const int tt = isq ? t : t - 1024;
    const int hh = tt >> 5, d = tt & 31;
    const int col = isq ? (hh * 64 + d) : (2048 + hh * 64 + d);
    float x1 = (float)qkv[(size_t)bs * QKVW + col];
    float x2 = (float)qkv[(size_t)bs * QKVW + col + 32];
    float fr = p * exp2f((float)d * -0.41524101186092029f);  // 10000^(-d/32)
    float sn, cs;
    sincosf(fr, &sn, &cs);
    float o1 = x1 * cs - x2 * sn;
    float o2 = x2 * cs + x1 * sn;
    if (isq) {
      o1 *= 0.125f; o2 *= 0.125f;       // fold softmax scale (exact pow2) into Q
      size_t base = (((size_t)b * NHEAD + hh) * SEQ + s) * HD + d;
      ql[base] = (bf16_t)o1; ql[base + 32] = (bf16_t)o2;
    } else {
      size_t base = (((size_t)b * NKVH + hh) * SEQ + s) * HD + d;
      kl[base] = (bf16_t)o1; kl[base + 32] = (bf16_t)o2;
    }
  }
}

// ---------------- V transpose: qkv v-slice -> vt (b,kvh,hd,s) ----------------
__global__ __launch_bounds__(256) void k_vtrans(const bf16_t* __restrict__ qkv,
                                                bf16_t* __restrict__ vt) {
  __shared__ bf16_t t[64][66];
  const int s0 = blockIdx.x * 64;
  const int bk = blockIdx.y;            // b*NKVH + kvh
  const int b = bk >> 3, kvh = bk & 7;
#pragma unroll
  for (int i = 0; i < 16; ++i) {
    int idx = threadIdx.x + i * 256;
    int r = idx >> 6, c = idx & 63;     // r = s offset, c = hd
    t[r][c] = qkv[((size_t)b * SEQ + s0 + r) * QKVW + 2560 + kvh * 64 + c];
  }
  __syncthreads();
#pragma unroll
  for (int i = 0; i < 16; ++i) {
    int idx = threadIdx.x + i * 256;
    int dr = idx >> 6, sc = idx & 63;
    vt[(((size_t)b * NKVH + kvh) * HD + dr) * SEQ + s0 + sc] = t[sc][dr];
  }
}

// ---------------- Flash attention, causal GQA, MFMA ----------------
// 1 wave = 32 q rows (2 m-frags); per-32-key chunk: 8 QK mfma -> online softmax
// (row stats in regs, shfl-xor over the 16-lane quad groups) -> P via per-wave
// LDS (C->A layout transform, m120 pattern) -> 8 PV mfma. Waves free-run.
__global__ __launch_bounds__(256) void k_attn(const bf16_t* __restrict__ ql,
                                              const bf16_t* __restrict__ kl,
                                              const bf16_t* __restrict__ vt,
                                              bf16_t* __restrict__ attn) {
  __shared__ __align__(16) bf16_t P[4][32 * 32];  // per-wave 2KB P buffer
  const int tile = blockIdx.x;          // S/128 tiles
  const int bh = blockIdx.y;            // b*NHEAD + h
  const int b = bh >> 5, h = bh & 31;
  const int kvh = h >> 2;               // GROUP=4
  const int wave = threadIdx.x >> 6, lane = threadIdx.x & 63;
  const int lr = lane & 15, quad = lane >> 4;
  const bf16_t* qp = ql + ((size_t)b * NHEAD + h) * SEQ * HD;
  const bf16_t* kp = kl + ((size_t)b * NKVH + kvh) * SEQ * HD;
  const bf16_t* vp = vt + ((size_t)b * NKVH + kvh) * HD * SEQ;
  const int q0 = tile * 128 + wave * 32;

  bf16x8 aq[2][2];
#pragma unroll
  for (int mf = 0; mf < 2; ++mf)
#pragma unroll
    for (int ks = 0; ks < 2; ++ks)
      aq[mf][ks] = *(const bf16x8*)(qp + (size_t)(q0 + mf * 16 + lr) * HD + ks * 32 + quad * 8);

  f32x4 acc[2][4];
  float mrow[2][4], lrow[2][4];
  const f32x4 z4 = {0.f, 0.f, 0.f, 0.f};
#pragma unroll
  for (int mf = 0; mf < 2; ++mf) {
#pragma unroll
    for (int nf = 0; nf < 4; ++nf) acc[mf][nf] = z4;
#pragma unroll
    for (int r = 0; r < 4; ++r) { mrow[mf][r] = -1e30f; lrow[mf][r] = 0.f; }
  }

  const int kcLast = q0 >> 5;           // keys up to q0+31 needed
  for (int kc = 0; kc <= kcLast; ++kc) {
    const int k0 = kc * 32;
    bf16x8 bk[2][2], bv[4];
#pragma unroll
    for (int ks = 0; ks < 2; ++ks)
#pragma unroll
      for (int nh = 0; nh < 2; ++nh)
        bk[ks][nh] = *(const bf16x8*)(kp + (size_t)(k0 + nh * 16 + lr) * HD + ks * 32 + quad * 8);
#pragma unroll
    for (int nf = 0; nf < 4; ++nf)
      bv[nf] = *(const bf16x8*)(vp + (size_t)(nf * 16 + lr) * SEQ + k0 + quad * 8);

    f32x4 sc[2][2];
#pragma unroll
    for (int mf = 0; mf < 2; ++mf)
#pragma unroll
      for (int nh = 0; nh < 2; ++nh) {
        sc[mf][nh] = __builtin_amdgcn_mfma_f32_16x16x32_bf16(aq[mf][0], bk[0][nh], z4, 0, 0, 0);
        sc[mf][nh] = __builtin_amdgcn_mfma_f32_16x16x32_bf16(aq[mf][1], bk[1][nh], sc[mf][nh], 0, 0, 0);
      }

    if (kc == kcLast) {                 // diagonal chunk: causal mask
#pragma unroll
      for (int mf = 0; mf < 2; ++mf)
#pragma unroll
        for (int nh = 0; nh < 2; ++nh)
#pragma unroll
          for (int r = 0; r < 4; ++r) {
            int qg = q0 + mf * 16 + quad * 4 + r;
            int kg = k0 + nh * 16 + lr;
            if (kg > qg) sc[mf][nh][r] = -1e30f;
          }
    }

#pragma unroll
    for (int mf = 0; mf < 2; ++mf) {
      float rm[4];
#pragma unroll
      for (int r = 0; r < 4; ++r) rm[r] = fmaxf(sc[mf][0][r], sc[mf][1][r]);
#pragma unroll
      for (int off = 1; off < 16; off <<= 1)
#pragma unroll
        for (int r = 0; r < 4; ++r) rm[r] = fmaxf(rm[r], __shfl_xor(rm[r], off, 64));
      float al[4], pv[2][4], rs[4];
#pragma unroll
      for (int r = 0; r < 4; ++r) {
        float mn = fmaxf(mrow[mf][r], rm[r]);
        al[r] = __expf(mrow[mf][r] - mn);
        mrow[mf][r] = mn;
      }
#pragma unroll
      for (int nh = 0; nh < 2; ++nh)
#pragma unroll
        for (int r = 0; r < 4; ++r) pv[nh][r] = __expf(sc[mf][nh][r] - mrow[mf][r]);
#pragma unroll
      for (int r = 0; r < 4; ++r) rs[r] = pv[0][r] + pv[1][r];
#pragma unroll
      for (int off = 1; off < 16; off <<= 1)
#pragma unroll
        for (int r = 0; r < 4; ++r) rs[r] += __shfl_xor(rs[r], off, 64);
#pragma unroll
      for (int r = 0; r < 4; ++r) lrow[mf][r] = lrow[mf][r] * al[r] + rs[r];
#pragma unroll
      for (int nf = 0; nf < 4; ++nf)
#pragma unroll
        for (int r = 0; r < 4; ++r) acc[mf][nf][r] *= al[r];
      bf16_t* pw = &P[wave][mf * 16 * 32];
#pragma unroll
      for (int nh = 0; nh < 2; ++nh)
#pragma unroll
        for (int r = 0; r < 4; ++r)
          pw[(quad * 4 + r) * 32 + nh * 16 + lr] = (bf16_t)pv[nh][r];
    }
    // per-wave LDS handoff (C-layout -> A-layout); DS pipe in-order per wave.
    __asm__ volatile("s_waitcnt lgkmcnt(0)" ::: "memory");
    bf16x8 pa[2];
#pragma unroll
    for (int mf = 0; mf < 2; ++mf)
      pa[mf] = *(const bf16x8*)(&P[wave][(mf * 16 + lr) * 32 + quad * 8]);
    __asm__ volatile("" ::: "memory");
#pragma unroll
    for (int mf = 0; mf < 2; ++mf)
#pragma unroll
      for (int nf = 0; nf < 4; ++nf)
        acc[mf][nf] = __builtin_amdgcn_mfma_f32_16x16x32_bf16(pa[mf], bv[nf], acc[mf][nf], 0, 0, 0);
  }

#pragma unroll
  for (int mf = 0; mf < 2; ++mf)
#pragma unroll
    for (int r = 0; r < 4; ++r) {
      float inv = 1.f / lrow[mf][r];
      int row = q0 + mf * 16 + quad * 4 + r;
#pragma unroll
      for (int nf = 0; nf < 4; ++nf)
        attn[((size_t)b * SEQ + row) * HIDDEN + h * HD + nf * 16 + lr] =
            (bf16_t)(acc[mf][nf][r] * inv);
    }
}

extern "C" void kernel_launch(void* const* d_in, const int* in_sizes, int n_in,
                              void* d_out, int out_size, void* d_ws, size_t ws_size,
                              hipStream_t stream) {
  float* out = (float*)d_out;

  // ---- contract checks (host-visible constants -> graph-safe) ----
  if (n_in != 4) { k_fill<<<dim3(32768), dim3(256), 0, stream>>>(out, 8388608, 222.0f); return; }
  if (out_size != 8388608) { k_fill<<<dim3(32768), dim3(256), 0, stream>>>(out, 8388608, 111.0f); return; }
  if (ws_size < (size_t)109051904) { k_fill<<<dim3(32768), dim3(256), 0, stream>>>(out, 8388608, 777.0f); return; }

  // ---- rank-match inputs by size (robust to input-order changes) ----
  int ord[4] = {0, 1, 2, 3};
  for (int i = 1; i < 4; ++i)
    for (int j = i; j > 0 && in_sizes[ord[j]] > in_sizes[ord[j - 1]]; --j) {
      int t = ord[j]; ord[j] = ord[j - 1]; ord[j - 1] = t;
    }
  const float*    hidden    = (const float*)d_in[ord[0]];  // 8388608 elems
  const float*    wqkv      = (const float*)d_in[ord[1]];  // 6291456
  const float*    wo        = (const float*)d_in[ord[2]];  // 4194304
  const unsigned* positions = (const unsigned*)d_in[ord[3]];  // 4096

  // ---- workspace, flat 100 MiB (no overlap; 128 MiB proven available) ----
  char* ws = (char*)d_ws;
  bf16_t* hidB  = (bf16_t*)(ws + 0);          // 16 MiB
  bf16_t* wqkvT = (bf16_t*)(ws + 16777216);   // 12 MiB
  bf16_t* woT   = (bf16_t*)(ws + 29360128);   //  8 MiB
  bf16_t* qkv   = (bf16_t*)(ws + 37748736);   // 24 MiB
  bf16_t* ql    = (bf16_t*)(ws + 62914560);   // 16 MiB
  bf16_t* kl    = (bf16_t*)(ws + 79691776);   //  4 MiB
  bf16_t* vt    = (bf16_t*)(ws + 83886080);   //  4 MiB
  bf16_t* attnb = (bf16_t*)(ws + 88080384);   // 16 MiB -> 104 MiB total

  k_cvt<<<dim3(8192), dim3(256), 0, stream>>>(hidden, hidB, 2097152);
  k_tconv<<<dim3(48, 32), dim3(256), 0, stream>>>(wqkv, wqkvT, 2048, 3072);
  k_tconv<<<dim3(32, 32), dim3(256), 0, stream>>>(wo, woT, 2048, 2048);
  k_gemm<bf16_t><<<dim3(24, 32), dim3(256), 0, stream>>>(hidB, wqkvT, qkv, 4096, 3072, 2048);
  k_rope<<<dim3(4096), dim3(256), 0, stream>>>(qkv, positions, ql, kl);
  k_vtrans<<<dim3(32, 16), dim3(256), 0, stream>>>(qkv, vt);
  k_attn<<<dim3(16, 64), dim3(256), 0, stream>>>(ql, kl, vt, attnb);
  k_gemm<float><<<dim3(16, 32), dim3(256), 0, stream>>>(attnb, woT, out, 4096, 2048, 2048);
}

// Round 10
// 465.110 us; speedup vs baseline: 19.3510x; 1.1161x over previous
//
#include <hip/hip_runtime.h>
#include <hip/hip_bf16.h>
#include <math.h>

#define SEQ 2048
#define HIDDEN 2048
#define NHEAD 32
#define NKVH 8
#define HD 64
#define QKVW 3072  // (NH + 2*NKV) * HD

typedef __bf16 bf16_t;
typedef __bf16 bf16x8 __attribute__((ext_vector_type(8)));
typedef __bf16 bf16x4 __attribute__((ext_vector_type(4)));
typedef float f32x4 __attribute__((ext_vector_type(4)));

__device__ __forceinline__ void gld_lds16(const bf16_t* g, bf16_t* l) {
  __builtin_amdgcn_global_load_lds((const __attribute__((address_space(1))) void*)g,
                                   (__attribute__((address_space(3))) void*)l, 16, 0, 0);
}

// ---------- sentinel fill (contract-violation signal), f32 ----------
__global__ __launch_bounds__(256) void k_fill(float* __restrict__ out, int n, float v) {
  int i = blockIdx.x * 256 + threadIdx.x;
  if (i < n) out[i] = v;
}

// ---------------- f32 -> bf16 convert, 4 elems/thread ----------------
__global__ __launch_bounds__(256) void k_cvt(const float* __restrict__ in,
                                             bf16_t* __restrict__ out, int n4) {
  int i = blockIdx.x * 256 + threadIdx.x;
  if (i >= n4) return;
  float4 v = ((const float4*)in)[i];
  bf16x4 o;
  o[0] = (bf16_t)v.x; o[1] = (bf16_t)v.y; o[2] = (bf16_t)v.z; o[3] = (bf16_t)v.w;
  ((bf16x4*)out)[i] = o;
}

// ------- transpose + convert: in (R x C) f32 row-major -> out (C x R) bf16 -------
__global__ __launch_bounds__(256) void k_tconv(const float* __restrict__ in,
                                               bf16_t* __restrict__ out, int R, int C) {
  __shared__ float t[64][65];
  const int c0 = blockIdx.x * 64, r0 = blockIdx.y * 64;
#pragma unroll
  for (int i = 0; i < 16; ++i) {
    int idx = threadIdx.x + i * 256;
    int r = idx >> 6, c = idx & 63;
    t[r][c] = in[(size_t)(r0 + r) * C + c0 + c];
  }
  __syncthreads();
#pragma unroll
  for (int i = 0; i < 16; ++i) {
    int idx = threadIdx.x + i * 256;
    int nr = idx >> 6, kc = idx & 63;
    out[(size_t)(c0 + nr) * R + r0 + kc] = (bf16_t)t[kc][nr];
  }
}

// ---------------- bf16 GEMM: C[M,N] = A[M,K] * Bt[N,K]^T ----------------
template <typename OutT>
__global__ __launch_bounds__(256) void k_gemm(const bf16_t* __restrict__ A,
                                              const bf16_t* __restrict__ Bt,
                                              OutT* __restrict__ C,
                                              int M, int N, int K) {
  __shared__ __align__(16) bf16_t As[128 * 32];
  __shared__ __align__(16) bf16_t Bs[128 * 32];
  const int tid  = threadIdx.x;
  const int wave = tid >> 6, lane = tid & 63;
  const int lr = lane & 15, quad = lane >> 4;
  const int mtile = blockIdx.y * 128, ntile = blockIdx.x * 128;
  const int wm = (wave & 1) * 64, wn = (wave >> 1) * 64;
  const int c0 = wave * 128 + lane, c1 = c0 + 64;

  const bf16_t* aG0 = A  + (size_t)(mtile + (c0 >> 2)) * K + (c0 & 3) * 8;
  const bf16_t* aG1 = A  + (size_t)(mtile + (c1 >> 2)) * K + (c1 & 3) * 8;
  const bf16_t* bG0 = Bt + (size_t)(ntile + (c0 >> 2)) * K + (c0 & 3) * 8;
  const bf16_t* bG1 = Bt + (size_t)(ntile + (c1 >> 2)) * K + (c1 & 3) * 8;
  bf16_t* lA0 = As + c0 * 8; bf16_t* lA1 = As + c1 * 8;
  bf16_t* lB0 = Bs + c0 * 8; bf16_t* lB1 = Bs + c1 * 8;

  f32x4 acc[4][4];
  const f32x4 z4 = {0.f, 0.f, 0.f, 0.f};
#pragma unroll
  for (int mf = 0; mf < 4; ++mf)
#pragma unroll
    for (int nf = 0; nf < 4; ++nf) acc[mf][nf] = z4;

  for (int kt = 0; kt < K; kt += 32) {
    bf16x8 va0 = *(const bf16x8*)(aG0 + kt);
    bf16x8 va1 = *(const bf16x8*)(aG1 + kt);
    bf16x8 vb0 = *(const bf16x8*)(bG0 + kt);
    bf16x8 vb1 = *(const bf16x8*)(bG1 + kt);
    __syncthreads();
    *(bf16x8*)lA0 = va0; *(bf16x8*)lA1 = va1;
    *(bf16x8*)lB0 = vb0; *(bf16x8*)lB1 = vb1;
    __syncthreads();
    bf16x8 af[4], bfr[4];
#pragma unroll
    for (int mf = 0; mf < 4; ++mf)
      af[mf] = *(const bf16x8*)(As + (wm + mf * 16 + lr) * 32 + quad * 8);
#pragma unroll
    for (int nf = 0; nf < 4; ++nf)
      bfr[nf] = *(const bf16x8*)(Bs + (wn + nf * 16 + lr) * 32 + quad * 8);
#pragma unroll
    for (int mf = 0; mf < 4; ++mf)
#pragma unroll
      for (int nf = 0; nf < 4; ++nf)
        acc[mf][nf] = __builtin_amdgcn_mfma_f32_16x16x32_bf16(af[mf], bfr[nf], acc[mf][nf], 0, 0, 0);
  }
#pragma unroll
  for (int mf = 0; mf < 4; ++mf)
#pragma unroll
    for (int nf = 0; nf < 4; ++nf)
#pragma unroll
      for (int r = 0; r < 4; ++r)
        C[(size_t)(mtile + wm + mf * 16 + quad * 4 + r) * N + ntile + wn + nf * 16 + lr] =
            (OutT)acc[mf][nf][r];
}

// -------- RoPE: qkv bf16 -> ql (b,h,s,hd)*0.125, kl (b,kvh,s,hd); pos adaptive --------
__global__ __launch_bounds__(256) void k_rope(const bf16_t* __restrict__ qkv,
                                              const unsigned* __restrict__ pos,
                                              bf16_t* __restrict__ ql,
                                              bf16_t* __restrict__ kl) {
  const int bs = blockIdx.x;
  const int b = bs >> 11, s = bs & 2047;
  const unsigned u = pos[bs];
  const float p = (u >= 0x3F800000u) ? __uint_as_float(u) : (float)(int)u;
  for (int t = threadIdx.x; t < 1280; t += 256) {
    const bool isq = t < 1024;
    const int tt = isq ? t : t - 1024;
    const int hh = tt >> 5, d = tt & 31;
    const int col = isq ? (hh * 64 + d) : (2048 + hh * 64 + d);
    float x1 = (float)qkv[(size_t)bs * QKVW + col];
    float x2 = (float)qkv[(size_t)bs * QKVW + col + 32];
    float fr = p * exp2f((float)d * -0.41524101186092029f);
    float sn, cs;
    sincosf(fr, &sn, &cs);
    float o1 = x1 * cs - x2 * sn;
    float o2 = x2 * cs + x1 * sn;
    if (isq) {
      o1 *= 0.125f; o2 *= 0.125f;
      size_t base = (((size_t)b * NHEAD + hh) * SEQ + s) * HD + d;
      ql[base] = (bf16_t)o1; ql[base + 32] = (bf16_t)o2;
    } else {
      size_t base = (((size_t)b * NKVH + hh) * SEQ + s) * HD + d;
      kl[base] = (bf16_t)o1; kl[base + 32] = (bf16_t)o2;
    }
  }
}

// ---------------- V transpose: qkv v-slice -> vt (b,kvh,hd,s) ----------------
__global__ __launch_bounds__(256) void k_vtrans(const bf16_t* __restrict__ qkv,
                                                bf16_t* __restrict__ vt) {
  __shared__ bf16_t t[64][66];
  const int s0 = blockIdx.x * 64;
  const int bk = blockIdx.y;
  const int b = bk >> 3, kvh = bk & 7;
#pragma unroll
  for (int i = 0; i < 16; ++i) {
    int idx = threadIdx.x + i * 256;
    int r = idx >> 6, c = idx & 63;
    t[r][c] = qkv[((size_t)b * SEQ + s0 + r) * QKVW + 2560 + kvh * 64 + c];
  }
  __syncthreads();
#pragma unroll
  for (int i = 0; i < 16; ++i) {
    int idx = threadIdx.x + i * 256;
    int dr = idx >> 6, sc = idx & 63;
    vt[(((size_t)b * NKVH + kvh) * HD + dr) * SEQ + s0 + sc] = t[sc][dr];
  }
}

// ---------------- Flash attention v2: cooperative LDS staging, 64-key tiles ----------------
// Block = 4 waves x 32 q-rows (128 rows of one (b,h)). Per 64-key tile: block stages
// K-tile (8KB) + Vt-tile (8KB) via global_load_lds; each wave: 16 QK mfma -> online
// softmax (shfl over quad groups) -> P via per-wave swizzled LDS -> 16 PV mfma.
// XOR swizzle (group ^ row&7) makes all b128 LDS reads conflict-free.
__global__ __launch_bounds__(256) void k_attn(const bf16_t* __restrict__ ql,
                                              const bf16_t* __restrict__ kl,
                                              const bf16_t* __restrict__ vt,
                                              bf16_t* __restrict__ attn) {
  __shared__ __align__(16) bf16_t Ks[64 * 64];   // [key][hd-group swizzled]
  __shared__ __align__(16) bf16_t Vs[64 * 64];   // [hd][key-group swizzled]
  __shared__ __align__(16) bf16_t P[4][32 * 64]; // per-wave, [row][key-group swizzled]
  const int tile = 15 - blockIdx.x;              // longest blocks dispatch first
  const int bh = blockIdx.y;
  const int b = bh >> 5, h = bh & 31;
  const int kvh = h >> 2;                        // GROUP=4
  const int wave = threadIdx.x >> 6, lane = threadIdx.x & 63;
  const int lr = lane & 15, quad = lane >> 4;
  const int lhi = lane >> 3, llo = lane & 7;     // staging decomposition
  const int gsw = llo ^ lhi;                     // swizzled source group (lhi<8)
  const bf16_t* qp = ql + ((size_t)b * NHEAD + h) * SEQ * HD;
  const bf16_t* kp = kl + ((size_t)b * NKVH + kvh) * SEQ * HD;
  const bf16_t* vp = vt + ((size_t)b * NKVH + kvh) * HD * SEQ;
  const int q0 = tile * 128 + wave * 32;

  bf16x8 aq[2][2];
#pragma unroll
  for (int mf = 0; mf < 2; ++mf)
#pragma unroll
    for (int ks = 0; ks < 2; ++ks)
      aq[mf][ks] = *(const bf16x8*)(qp + (size_t)(q0 + mf * 16 + lr) * HD + ks * 32 + quad * 8);

  f32x4 acc[2][4];
  float mrow[2][4], lrow[2][4];
  const f32x4 z4 = {0.f, 0.f, 0.f, 0.f};
#pragma unroll
  for (int mf = 0; mf < 2; ++mf) {
#pragma unroll
    for (int nf = 0; nf < 4; ++nf) acc[mf][nf] = z4;
#pragma unroll
    for (int r = 0; r < 4; ++r) { mrow[mf][r] = -1e30f; lrow[mf][r] = 0.f; }
  }

  const int ntiles = 2 * tile + 2;               // uniform per block (barrier-safe)
  for (int kt = 0; kt < ntiles; ++kt) {
    const int k0 = kt * 64;
    __syncthreads();                             // prior tile's LDS reads complete
    {
      const bf16_t* kbase = kp + (size_t)k0 * HD;
#pragma unroll
      for (int j = 0; j < 2; ++j) {              // Ks: keys (wave*2+j)*8+lhi
        int key = (wave * 2 + j) * 8 + lhi;
        gld_lds16(kbase + key * HD + gsw * 8, Ks + (wave * 2 + j) * 512 + lane * 8);
      }
#pragma unroll
      for (int j = 0; j < 2; ++j) {              // Vs: hd rows wave*16+j*8+lhi
        int hd = wave * 16 + j * 8 + lhi;
        gld_lds16(vp + (size_t)hd * SEQ + k0 + gsw * 8, Vs + (wave * 16 + j * 8) * 64 + lane * 8);
      }
    }
    __syncthreads();                             // tiles resident (vmcnt drained)
    if (k0 > q0 + 31) continue;                  // wave fully masked; keep barrier cadence

    bf16x8 bk[2][4];
#pragma unroll
    for (int ks = 0; ks < 2; ++ks)
#pragma unroll
      for (int nh = 0; nh < 4; ++nh)
        bk[ks][nh] = *(const bf16x8*)(Ks + (nh * 16 + lr) * 64 + (((ks * 4 + quad) ^ (lr & 7)) << 3));
    f32x4 sc[2][4];
#pragma unroll
    for (int mf = 0; mf < 2; ++mf)
#pragma unroll
      for (int nh = 0; nh < 4; ++nh) {
        sc[mf][nh] = __builtin_amdgcn_mfma_f32_16x16x32_bf16(aq[mf][0], bk[0][nh], z4, 0, 0, 0);
        sc[mf][nh] = __builtin_amdgcn_mfma_f32_16x16x32_bf16(aq[mf][1], bk[1][nh], sc[mf][nh], 0, 0, 0);
      }

    if (k0 + 63 > q0) {                          // diagonal tile: causal mask
#pragma unroll
      for (int mf = 0; mf < 2; ++mf)
#pragma unroll
        for (int nh = 0; nh < 4; ++nh)
#pragma unroll
          for (int r = 0; r < 4; ++r) {
            int qg = q0 + mf * 16 + quad * 4 + r;
            int kg = k0 + nh * 16 + lr;
            if (kg > qg) sc[mf][nh][r] = -1e30f;
          }
    }

#pragma unroll
    for (int mf = 0; mf < 2; ++mf) {
      float rm[4];
#pragma unroll
      for (int r = 0; r < 4; ++r)
        rm[r] = fmaxf(fmaxf(sc[mf][0][r], sc[mf][1][r]), fmaxf(sc[mf][2][r], sc[mf][3][r]));
#pragma unroll
      for (int off = 1; off < 16; off <<= 1)
#pragma unroll
        for (int r = 0; r < 4; ++r) rm[r] = fmaxf(rm[r], __shfl_xor(rm[r], off, 64));
      float al[4], rs[4];
#pragma unroll
      for (int r = 0; r < 4; ++r) {
        float mn = fmaxf(mrow[mf][r], rm[r]);
        al[r] = __expf(mrow[mf][r] - mn);
        mrow[mf][r] = mn;
      }
#pragma unroll
      for (int nh = 0; nh < 4; ++nh)
#pragma unroll
        for (int r = 0; r < 4; ++r) sc[mf][nh][r] = __expf(sc[mf][nh][r] - mrow[mf][r]);
#pragma unroll
      for (int r = 0; r < 4; ++r)
        rs[r] = (sc[mf][0][r] + sc[mf][1][r]) + (sc[mf][2][r] + sc[mf][3][r]);
#pragma unroll
      for (int off = 1; off < 16; off <<= 1)
#pragma unroll
        for (int r = 0; r < 4; ++r) rs[r] += __shfl_xor(rs[r], off, 64);
#pragma unroll
      for (int r = 0; r < 4; ++r) lrow[mf][r] = lrow[mf][r] * al[r] + rs[r];
#pragma unroll
      for (int nf = 0; nf < 4; ++nf)
#pragma unroll
        for (int r = 0; r < 4; ++r) acc[mf][nf][r] *= al[r];
      // P write: (row=mf*16+quad*4+r, col=nh*16+lr), swizzled col-group
#pragma unroll
      for (int nh = 0; nh < 4; ++nh)
#pragma unroll
        for (int r = 0; r < 4; ++r) {
          int row = mf * 16 + quad * 4 + r;
          int cg = (nh * 2 + (lr >> 3)) ^ (row & 7);
          P[wave][row * 64 + (cg << 3) + (lr & 7)] = (bf16_t)sc[mf][nh][r];
        }
    }
    // per-wave C->A handoff; DS pipe in-order, pin compiler ordering + drain
    __asm__ volatile("s_waitcnt lgkmcnt(0)" ::: "memory");
    bf16x8 pa[2][2], bv[2][4];
#pragma unroll
    for (int mf = 0; mf < 2; ++mf)
#pragma unroll
      for (int kg = 0; kg < 2; ++kg)
        pa[mf][kg] = *(const bf16x8*)(&P[wave][(mf * 16 + lr) * 64 + (((kg * 4 + quad) ^ (lr & 7)) << 3)]);
#pragma unroll
    for (int kg = 0; kg < 2; ++kg)
#pragma unroll
      for (int nf = 0; nf < 4; ++nf)
        bv[kg][nf] = *(const bf16x8*)(Vs + (nf * 16 + lr) * 64 + (((kg * 4 + quad) ^ (lr & 7)) << 3));
    __asm__ volatile("" ::: "memory");
#pragma unroll
    for (int mf = 0; mf < 2; ++mf)
#pragma unroll
      for (int nf = 0; nf < 4; ++nf) {
        acc[mf][nf] = __builtin_amdgcn_mfma_f32_16x16x32_bf16(pa[mf][0], bv[0][nf], acc[mf][nf], 0, 0, 0);
        acc[mf][nf] = __builtin_amdgcn_mfma_f32_16x16x32_bf16(pa[mf][1], bv[1][nf], acc[mf][nf], 0, 0, 0);
      }
  }

#pragma unroll
  for (int mf = 0; mf < 2; ++mf)
#pragma unroll
    for (int r = 0; r < 4; ++r) {
      float inv = 1.f / lrow[mf][r];
      int row = q0 + mf * 16 + quad * 4 + r;
#pragma unroll
      for (int nf = 0; nf < 4; ++nf)
        attn[((size_t)b * SEQ + row) * HIDDEN + h * HD + nf * 16 + lr] =
            (bf16_t)(acc[mf][nf][r] * inv);
    }
}

extern "C" void kernel_launch(void* const* d_in, const int* in_sizes, int n_in,
                              void* d_out, int out_size, void* d_ws, size_t ws_size,
                              hipStream_t stream) {
  float* out = (float*)d_out;

  if (n_in != 4) { k_fill<<<dim3(32768), dim3(256), 0, stream>>>(out, 8388608, 222.0f); return; }
  if (out_size != 8388608) { k_fill<<<dim3(32768), dim3(256), 0, stream>>>(out, 8388608, 111.0f); return; }
  if (ws_size < (size_t)109051904) { k_fill<<<dim3(32768), dim3(256), 0, stream>>>(out, 8388608, 777.0f); return; }

  int ord[4] = {0, 1, 2, 3};
  for (int i = 1; i < 4; ++i)
    for (int j = i; j > 0 && in_sizes[ord[j]] > in_sizes[ord[j - 1]]; --j) {
      int t = ord[j]; ord[j] = ord[j - 1]; ord[j - 1] = t;
    }
  const float*    hidden    = (const float*)d_in[ord[0]];
  const float*    wqkv      = (const float*)d_in[ord[1]];
  const float*    wo        = (const float*)d_in[ord[2]];
  const unsigned* positions = (const unsigned*)d_in[ord[3]];

  char* ws = (char*)d_ws;
  bf16_t* hidB  = (bf16_t*)(ws + 0);
  bf16_t* wqkvT = (bf16_t*)(ws + 16777216);
  bf16_t* woT   = (bf16_t*)(ws + 29360128);
  bf16_t* qkv   = (bf16_t*)(ws + 37748736);
  bf16_t* ql    = (bf16_t*)(ws + 62914560);
  bf16_t* kl    = (bf16_t*)(ws + 79691776);
  bf16_t* vt    = (bf16_t*)(ws + 83886080);
  bf16_t* attnb = (bf16_t*)(ws + 88080384);

  k_cvt<<<dim3(8192), dim3(256), 0, stream>>>(hidden, hidB, 2097152);
  k_tconv<<<dim3(48, 32), dim3(256), 0, stream>>>(wqkv, wqkvT, 2048, 3072);
  k_tconv<<<dim3(32, 32), dim3(256), 0, stream>>>(wo, woT, 2048, 2048);
  k_gemm<bf16_t><<<dim3(24, 32), dim3(256), 0, stream>>>(hidB, wqkvT, qkv, 4096, 3072, 2048);
  k_rope<<<dim3(4096), dim3(256), 0, stream>>>(qkv, positions, ql, kl);
  k_vtrans<<<dim3(32, 16), dim3(256), 0, stream>>>(qkv, vt);
  k_attn<<<dim3(16, 64), dim3(256), 0, stream>>>(ql, kl, vt, attnb);
  k_gemm<float><<<dim3(16, 32), dim3(256), 0, stream>>>(attnb, woT, out, 4096, 2048, 2048);
}

// Round 11
// 429.084 us; speedup vs baseline: 20.9758x; 1.0840x over previous
//
#include <hip/hip_runtime.h>
#include <hip/hip_bf16.h>
#include <math.h>

#define SEQ 2048
#define HIDDEN 2048
#define NHEAD 32
#define NKVH 8
#define HD 64
#define QKVW 3072  // (NH + 2*NKV) * HD

typedef __bf16 bf16_t;
typedef __bf16 bf16x8 __attribute__((ext_vector_type(8)));
typedef __bf16 bf16x4 __attribute__((ext_vector_type(4)));
typedef float f32x4 __attribute__((ext_vector_type(4)));

__device__ __forceinline__ void gld_lds16(const bf16_t* g, bf16_t* l) {
  __builtin_amdgcn_global_load_lds((const __attribute__((address_space(1))) void*)g,
                                   (__attribute__((address_space(3))) void*)l, 16, 0, 0);
}

// ---------- sentinel fill (contract-violation signal), f32 ----------
__global__ __launch_bounds__(256) void k_fill(float* __restrict__ out, int n, float v) {
  int i = blockIdx.x * 256 + threadIdx.x;
  if (i < n) out[i] = v;
}

// ---------------- f32 -> bf16 convert, 4 elems/thread ----------------
__global__ __launch_bounds__(256) void k_cvt(const float* __restrict__ in,
                                             bf16_t* __restrict__ out, int n4) {
  int i = blockIdx.x * 256 + threadIdx.x;
  if (i >= n4) return;
  float4 v = ((const float4*)in)[i];
  bf16x4 o;
  o[0] = (bf16_t)v.x; o[1] = (bf16_t)v.y; o[2] = (bf16_t)v.z; o[3] = (bf16_t)v.w;
  ((bf16x4*)out)[i] = o;
}

// ------- transpose + convert: in (R x C) f32 row-major -> out (C x R) bf16 -------
__global__ __launch_bounds__(256) void k_tconv(const float* __restrict__ in,
                                               bf16_t* __restrict__ out, int R, int C) {
  __shared__ float t[64][65];
  const int c0 = blockIdx.x * 64, r0 = blockIdx.y * 64;
#pragma unroll
  for (int i = 0; i < 16; ++i) {
    int idx = threadIdx.x + i * 256;
    int r = idx >> 6, c = idx & 63;
    t[r][c] = in[(size_t)(r0 + r) * C + c0 + c];
  }
  __syncthreads();
#pragma unroll
  for (int i = 0; i < 16; ++i) {
    int idx = threadIdx.x + i * 256;
    int nr = idx >> 6, kc = idx & 63;
    out[(size_t)(c0 + nr) * R + r0 + kc] = (bf16_t)t[kc][nr];
  }
}

// ---------------- bf16 GEMM: C[M,N] = A[M,K] * Bt[N,K]^T ----------------
template <typename OutT>
__global__ __launch_bounds__(256) void k_gemm(const bf16_t* __restrict__ A,
                                              const bf16_t* __restrict__ Bt,
                                              OutT* __restrict__ C,
                                              int M, int N, int K) {
  __shared__ __align__(16) bf16_t As[128 * 32];
  __shared__ __align__(16) bf16_t Bs[128 * 32];
  const int tid  = threadIdx.x;
  const int wave = tid >> 6, lane = tid & 63;
  const int lr = lane & 15, quad = lane >> 4;
  const int mtile = blockIdx.y * 128, ntile = blockIdx.x * 128;
  const int wm = (wave & 1) * 64, wn = (wave >> 1) * 64;
  const int c0 = wave * 128 + lane, c1 = c0 + 64;

  const bf16_t* aG0 = A  + (size_t)(mtile + (c0 >> 2)) * K + (c0 & 3) * 8;
  const bf16_t* aG1 = A  + (size_t)(mtile + (c1 >> 2)) * K + (c1 & 3) * 8;
  const bf16_t* bG0 = Bt + (size_t)(ntile + (c0 >> 2)) * K + (c0 & 3) * 8;
  const bf16_t* bG1 = Bt + (size_t)(ntile + (c1 >> 2)) * K + (c1 & 3) * 8;
  bf16_t* lA0 = As + c0 * 8; bf16_t* lA1 = As + c1 * 8;
  bf16_t* lB0 = Bs + c0 * 8; bf16_t* lB1 = Bs + c1 * 8;

  f32x4 acc[4][4];
  const f32x4 z4 = {0.f, 0.f, 0.f, 0.f};
#pragma unroll
  for (int mf = 0; mf < 4; ++mf)
#pragma unroll
    for (int nf = 0; nf < 4; ++nf) acc[mf][nf] = z4;

  for (int kt = 0; kt < K; kt += 32) {
    bf16x8 va0 = *(const bf16x8*)(aG0 + kt);
    bf16x8 va1 = *(const bf16x8*)(aG1 + kt);
    bf16x8 vb0 = *(const bf16x8*)(bG0 + kt);
    bf16x8 vb1 = *(const bf16x8*)(bG1 + kt);
    __syncthreads();
    *(bf16x8*)lA0 = va0; *(bf16x8*)lA1 = va1;
    *(bf16x8*)lB0 = vb0; *(bf16x8*)lB1 = vb1;
    __syncthreads();
    bf16x8 af[4], bfr[4];
#pragma unroll
    for (int mf = 0; mf < 4; ++mf)
      af[mf] = *(const bf16x8*)(As + (wm + mf * 16 + lr) * 32 + quad * 8);
#pragma unroll
    for (int nf = 0; nf < 4; ++nf)
      bfr[nf] = *(const bf16x8*)(Bs + (wn + nf * 16 + lr) * 32 + quad * 8);
#pragma unroll
    for (int mf = 0; mf < 4; ++mf)
#pragma unroll
      for (int nf = 0; nf < 4; ++nf)
        acc[mf][nf] = __builtin_amdgcn_mfma_f32_16x16x32_bf16(af[mf], bfr[nf], acc[mf][nf], 0, 0, 0);
  }
#pragma unroll
  for (int mf = 0; mf < 4; ++mf)
#pragma unroll
    for (int nf = 0; nf < 4; ++nf)
#pragma unroll
      for (int r = 0; r < 4; ++r)
        C[(size_t)(mtile + wm + mf * 16 + quad * 4 + r) * N + ntile + wn + nf * 16 + lr] =
            (OutT)acc[mf][nf][r];
}

// -------- RoPE: qkv bf16 -> ql (b,h,s,hd)*0.125, kl (b,kvh,s,hd); pos adaptive --------
__global__ __launch_bounds__(256) void k_rope(const bf16_t* __restrict__ qkv,
                                              const unsigned* __restrict__ pos,
                                              bf16_t* __restrict__ ql,
                                              bf16_t* __restrict__ kl) {
  const int bs = blockIdx.x;
  const int b = bs >> 11, s = bs & 2047;
  const unsigned u = pos[bs];
  const float p = (u >= 0x3F800000u) ? __uint_as_float(u) : (float)(int)u;
  for (int t = threadIdx.x; t < 1280; t += 256) {
    const bool isq = t < 1024;
    const int tt = isq ? t : t - 1024;
    const int hh = tt >> 5, d = tt & 31;
    const int col = isq ? (hh * 64 + d) : (2048 + hh * 64 + d);
    float x1 = (float)qkv[(size_t)bs * QKVW + col];
    float x2 = (float)qkv[(size_t)bs * QKVW + col + 32];
    float fr = p * exp2f((float)d * -0.41524101186092029f);
    float sn, cs;
    sincosf(fr, &sn, &cs);
    float o1 = x1 * cs - x2 * sn;
    float o2 = x2 * cs + x1 * sn;
    if (isq) {
      o1 *= 0.125f; o2 *= 0.125f;
      size_t base = (((size_t)b * NHEAD + hh) * SEQ + s) * HD + d;
      ql[base] = (bf16_t)o1; ql[base + 32] = (bf16_t)o2;
    } else {
      size_t base = (((size_t)b * NKVH + hh) * SEQ + s) * HD + d;
      kl[base] = (bf16_t)o1; kl[base + 32] = (bf16_t)o2;
    }
  }
}

// ---------------- V transpose: qkv v-slice -> vt (b,kvh,hd,s) ----------------
__global__ __launch_bounds__(256) void k_vtrans(const bf16_t* __restrict__ qkv,
                                                bf16_t* __restrict__ vt) {
  __shared__ bf16_t t[64][66];
  const int s0 = blockIdx.x * 64;
  const int bk = blockIdx.y;
  const int b = bk >> 3, kvh = bk & 7;
#pragma unroll
  for (int i = 0; i < 16; ++i) {
    int idx = threadIdx.x + i * 256;
    int r = idx >> 6, c = idx & 63;
    t[r][c] = qkv[((size_t)b * SEQ + s0 + r) * QKVW + 2560 + kvh * 64 + c];
  }
  __syncthreads();
#pragma unroll
  for (int i = 0; i < 16; ++i) {
    int idx = threadIdx.x + i * 256;
    int dr = idx >> 6, sc = idx & 63;
    vt[(((size_t)b * NKVH + kvh) * HD + dr) * SEQ + s0 + sc] = t[sc][dr];
  }
}

// ---------------- Flash attention v3: paired q-tiles (uniform blocks) ----------------
// Block = 4 waves; processes q-tile (15-p) then q-tile p sequentially -> every block
// does exactly 34 k-tiles (load-balanced; no triangular tail). Per 64-key tile:
// cooperative LDS staging (global_load_lds w16, XOR-swizzled), 16 QK mfma, softmax
// with BOTH m-frags' shfl reductions in flight, P via per-wave swizzled LDS, 16 PV mfma.
__global__ __launch_bounds__(256) void k_attn(const bf16_t* __restrict__ ql,
                                              const bf16_t* __restrict__ kl,
                                              const bf16_t* __restrict__ vt,
                                              bf16_t* __restrict__ attn) {
  __shared__ __align__(16) bf16_t Ks[64 * 64];
  __shared__ __align__(16) bf16_t Vs[64 * 64];
  __shared__ __align__(16) bf16_t P[4][32 * 64];
  const int pairp = blockIdx.x;                  // 0..7
  const int bh = blockIdx.y;
  const int b = bh >> 5, h = bh & 31;
  const int kvh = h >> 2;                        // GROUP=4
  const int wave = threadIdx.x >> 6, lane = threadIdx.x & 63;
  const int lr = lane & 15, quad = lane >> 4;
  const int lhi = lane >> 3, llo = lane & 7;
  const int gsw = llo ^ lhi;
  const bf16_t* qp = ql + ((size_t)b * NHEAD + h) * SEQ * HD;
  const bf16_t* kp = kl + ((size_t)b * NKVH + kvh) * SEQ * HD;
  const bf16_t* vp = vt + ((size_t)b * NKVH + kvh) * HD * SEQ;
  const f32x4 z4 = {0.f, 0.f, 0.f, 0.f};

#pragma unroll
  for (int seg = 0; seg < 2; ++seg) {
    const int tile = seg ? pairp : 15 - pairp;   // long tile first
    const int q0 = tile * 128 + wave * 32;

    bf16x8 aq[2][2];
#pragma unroll
    for (int mf = 0; mf < 2; ++mf)
#pragma unroll
      for (int ks = 0; ks < 2; ++ks)
        aq[mf][ks] = *(const bf16x8*)(qp + (size_t)(q0 + mf * 16 + lr) * HD + ks * 32 + quad * 8);

    f32x4 acc[2][4];
    float mrow[2][4], lrow[2][4];
#pragma unroll
    for (int mf = 0; mf < 2; ++mf) {
#pragma unroll
      for (int nf = 0; nf < 4; ++nf) acc[mf][nf] = z4;
#pragma unroll
      for (int r = 0; r < 4; ++r) { mrow[mf][r] = -1e30f; lrow[mf][r] = 0.f; }
    }

    const int ntiles = 2 * tile + 2;             // uniform per block segment
    for (int kt = 0; kt < ntiles; ++kt) {
      const int k0 = kt * 64;
      __syncthreads();                           // prior tile's LDS reads complete
      {
        const bf16_t* kbase = kp + (size_t)k0 * HD;
#pragma unroll
        for (int j = 0; j < 2; ++j) {
          int key = (wave * 2 + j) * 8 + lhi;
          gld_lds16(kbase + key * HD + gsw * 8, Ks + (wave * 2 + j) * 512 + lane * 8);
        }
#pragma unroll
        for (int j = 0; j < 2; ++j) {
          int hd = wave * 16 + j * 8 + lhi;
          gld_lds16(vp + (size_t)hd * SEQ + k0 + gsw * 8, Vs + (wave * 16 + j * 8) * 64 + lane * 8);
        }
      }
      __syncthreads();                           // tiles resident
      if (k0 > q0 + 31) continue;                // masked wave keeps barrier cadence

      bf16x8 bk[2][4];
#pragma unroll
      for (int ks = 0; ks < 2; ++ks)
#pragma unroll
        for (int nh = 0; nh < 4; ++nh)
          bk[ks][nh] = *(const bf16x8*)(Ks + (nh * 16 + lr) * 64 + (((ks * 4 + quad) ^ (lr & 7)) << 3));
      f32x4 sc[2][4];
#pragma unroll
      for (int mf = 0; mf < 2; ++mf)
#pragma unroll
        for (int nh = 0; nh < 4; ++nh) {
          sc[mf][nh] = __builtin_amdgcn_mfma_f32_16x16x32_bf16(aq[mf][0], bk[0][nh], z4, 0, 0, 0);
          sc[mf][nh] = __builtin_amdgcn_mfma_f32_16x16x32_bf16(aq[mf][1], bk[1][nh], sc[mf][nh], 0, 0, 0);
        }

      if (k0 + 63 > q0) {                        // diagonal tile: causal mask
#pragma unroll
        for (int mf = 0; mf < 2; ++mf)
#pragma unroll
          for (int nh = 0; nh < 4; ++nh)
#pragma unroll
            for (int r = 0; r < 4; ++r) {
              int qg = q0 + mf * 16 + quad * 4 + r;
              int kg = k0 + nh * 16 + lr;
              if (kg > qg) sc[mf][nh][r] = -1e30f;
            }
      }

      // online softmax: both m-frags' reductions in flight (8 values per hop)
      float rm[2][4], al[2][4], rs[2][4];
#pragma unroll
      for (int mf = 0; mf < 2; ++mf)
#pragma unroll
        for (int r = 0; r < 4; ++r)
          rm[mf][r] = fmaxf(fmaxf(sc[mf][0][r], sc[mf][1][r]), fmaxf(sc[mf][2][r], sc[mf][3][r]));
#pragma unroll
      for (int off = 1; off < 16; off <<= 1)
#pragma unroll
        for (int mf = 0; mf < 2; ++mf)
#pragma unroll
          for (int r = 0; r < 4; ++r) rm[mf][r] = fmaxf(rm[mf][r], __shfl_xor(rm[mf][r], off, 64));
#pragma unroll
      for (int mf = 0; mf < 2; ++mf)
#pragma unroll
        for (int r = 0; r < 4; ++r) {
          float mn = fmaxf(mrow[mf][r], rm[mf][r]);
          al[mf][r] = __expf(mrow[mf][r] - mn);
          mrow[mf][r] = mn;
        }
#pragma unroll
      for (int mf = 0; mf < 2; ++mf)
#pragma unroll
        for (int nh = 0; nh < 4; ++nh)
#pragma unroll
          for (int r = 0; r < 4; ++r) sc[mf][nh][r] = __expf(sc[mf][nh][r] - mrow[mf][r]);
#pragma unroll
      for (int mf = 0; mf < 2; ++mf)
#pragma unroll
        for (int r = 0; r < 4; ++r)
          rs[mf][r] = (sc[mf][0][r] + sc[mf][1][r]) + (sc[mf][2][r] + sc[mf][3][r]);
#pragma unroll
      for (int off = 1; off < 16; off <<= 1)
#pragma unroll
        for (int mf = 0; mf < 2; ++mf)
#pragma unroll
          for (int r = 0; r < 4; ++r) rs[mf][r] += __shfl_xor(rs[mf][r], off, 64);
#pragma unroll
      for (int mf = 0; mf < 2; ++mf) {
#pragma unroll
        for (int r = 0; r < 4; ++r) lrow[mf][r] = lrow[mf][r] * al[mf][r] + rs[mf][r];
#pragma unroll
        for (int nf = 0; nf < 4; ++nf)
#pragma unroll
          for (int r = 0; r < 4; ++r) acc[mf][nf][r] *= al[mf][r];
#pragma unroll
        for (int nh = 0; nh < 4; ++nh)
#pragma unroll
          for (int r = 0; r < 4; ++r) {
            int row = mf * 16 + quad * 4 + r;
            int cg = (nh * 2 + (lr >> 3)) ^ (row & 7);
            P[wave][row * 64 + (cg << 3) + (lr & 7)] = (bf16_t)sc[mf][nh][r];
          }
      }
      // per-wave C->A handoff; DS pipe in-order per wave
      __asm__ volatile("s_waitcnt lgkmcnt(0)" ::: "memory");
      bf16x8 pa[2][2], bv[2][4];
#pragma unroll
      for (int mf = 0; mf < 2; ++mf)
#pragma unroll
        for (int kg = 0; kg < 2; ++kg)
          pa[mf][kg] = *(const bf16x8*)(&P[wave][(mf * 16 + lr) * 64 + (((kg * 4 + quad) ^ (lr & 7)) << 3)]);
#pragma unroll
      for (int kg = 0; kg < 2; ++kg)
#pragma unroll
        for (int nf = 0; nf < 4; ++nf)
          bv[kg][nf] = *(const bf16x8*)(Vs + (nf * 16 + lr) * 64 + (((kg * 4 + quad) ^ (lr & 7)) << 3));
      __asm__ volatile("" ::: "memory");
#pragma unroll
      for (int mf = 0; mf < 2; ++mf)
#pragma unroll
        for (int nf = 0; nf < 4; ++nf) {
          acc[mf][nf] = __builtin_amdgcn_mfma_f32_16x16x32_bf16(pa[mf][0], bv[0][nf], acc[mf][nf], 0, 0, 0);
          acc[mf][nf] = __builtin_amdgcn_mfma_f32_16x16x32_bf16(pa[mf][1], bv[1][nf], acc[mf][nf], 0, 0, 0);
        }
    }

#pragma unroll
    for (int mf = 0; mf < 2; ++mf)
#pragma unroll
      for (int r = 0; r < 4; ++r) {
        float inv = 1.f / lrow[mf][r];
        int row = q0 + mf * 16 + quad * 4 + r;
#pragma unroll
        for (int nf = 0; nf < 4; ++nf)
          attn[((size_t)b * SEQ + row) * HIDDEN + h * HD + nf * 16 + lr] =
              (bf16_t)(acc[mf][nf][r] * inv);
      }
  }
}

extern "C" void kernel_launch(void* const* d_in, const int* in_sizes, int n_in,
                              void* d_out, int out_size, void* d_ws, size_t ws_size,
                              hipStream_t stream) {
  float* out = (float*)d_out;

  if (n_in != 4) { k_fill<<<dim3(32768), dim3(256), 0, stream>>>(out, 8388608, 222.0f); return; }
  if (out_size != 8388608) { k_fill<<<dim3(32768), dim3(256), 0, stream>>>(out, 8388608, 111.0f); return; }
  if (ws_size < (size_t)109051904) { k_fill<<<dim3(32768), dim3(256), 0, stream>>>(out, 8388608, 777.0f); return; }

  int ord[4] = {0, 1, 2, 3};
  for (int i = 1; i < 4; ++i)
    for (int j = i; j > 0 && in_sizes[ord[j]] > in_sizes[ord[j - 1]]; --j) {
      int t = ord[j]; ord[j] = ord[j - 1]; ord[j - 1] = t;
    }
  const float*    hidden    = (const float*)d_in[ord[0]];
  const float*    wqkv      = (const float*)d_in[ord[1]];
  const float*    wo        = (const float*)d_in[ord[2]];
  const unsigned* positions = (const unsigned*)d_in[ord[3]];

  char* ws = (char*)d_ws;
  bf16_t* hidB  = (bf16_t*)(ws + 0);
  bf16_t* wqkvT = (bf16_t*)(ws + 16777216);
  bf16_t* woT   = (bf16_t*)(ws + 29360128);
  bf16_t* qkv   = (bf16_t*)(ws + 37748736);
  bf16_t* ql    = (bf16_t*)(ws + 62914560);
  bf16_t* kl    = (bf16_t*)(ws + 79691776);
  bf16_t* vt    = (bf16_t*)(ws + 83886080);
  bf16_t* attnb = (bf16_t*)(ws + 88080384);

  k_cvt<<<dim3(8192), dim3(256), 0, stream>>>(hidden, hidB, 2097152);
  k_tconv<<<dim3(48, 32), dim3(256), 0, stream>>>(wqkv, wqkvT, 2048, 3072);
  k_tconv<<<dim3(32, 32), dim3(256), 0, stream>>>(wo, woT, 2048, 2048);
  k_gemm<bf16_t><<<dim3(24, 32), dim3(256), 0, stream>>>(hidB, wqkvT, qkv, 4096, 3072, 2048);
  k_rope<<<dim3(4096), dim3(256), 0, stream>>>(qkv, positions, ql, kl);
  k_vtrans<<<dim3(32, 16), dim3(256), 0, stream>>>(qkv, vt);
  k_attn<<<dim3(8, 64), dim3(256), 0, stream>>>(ql, kl, vt, attnb);
  k_gemm<float><<<dim3(16, 32), dim3(256), 0, stream>>>(attnb, woT, out, 4096, 2048, 2048);
}